// Round 11
// baseline (1722.327 us; speedup 1.0000x reference)
//
#include <hip/hip_runtime.h>
#include <cmath>

#define BB 64
#define TT 2048
#define FF 64
#define HH 160
#define G3 480
#define TC 128            // time-chunk length (buffer granule)
#define NC (TT / TC)      // 16 chunks
#define NHS 35            // half-chunk pipeline stages: 2*NC + 3

#define L2E  1.44269504088896340736f
#define TL2E 2.88539008177792681472f

typedef unsigned int u32;
typedef _Float16 half8 __attribute__((ext_vector_type(8)));
typedef _Float16 half2v __attribute__((ext_vector_type(2)));
typedef float f32x4 __attribute__((ext_vector_type(4)));

__device__ __forceinline__ unsigned short f2h(float v) {
    _Float16 h = (_Float16)v;
    return __builtin_bit_cast(unsigned short, h);
}
__device__ __forceinline__ u32 packh2(float a, float b) {
    return (u32)f2h(a) | ((u32)f2h(b) << 16);
}
__device__ __forceinline__ u32 packhh(_Float16 a, _Float16 b) {
    return (u32)__builtin_bit_cast(unsigned short, a)
         | ((u32)__builtin_bit_cast(unsigned short, b) << 16);
}
// select f16 half by precomputed shift (0 or 16), then convert
__device__ __forceinline__ float h2sel(u32 p, u32 sh) {
    return (float)__builtin_bit_cast(half2v, p >> sh)[0];
}
// fast 1-ulp reciprocal / exp2 (avoid IEEE div + libm: no fast-math in harness)
__device__ __forceinline__ float frcp(float v) { return __builtin_amdgcn_rcpf(v); }
#if __has_builtin(__builtin_amdgcn_exp2f)
__device__ __forceinline__ float fexp2(float v) { return __builtin_amdgcn_exp2f(v); }
#else
__device__ __forceinline__ float fexp2(float v) { return __expf(v * 0.69314718055994530942f); }
#endif
__device__ __forceinline__ float gelu_exact(float v) {
    return 0.5f * v * (1.f + erff(v * 0.70710678118654752f));
}
// barrier that waits only on LDS ops (NOT vmcnt)
__device__ __forceinline__ void barrier_lgkm() {
    asm volatile("s_waitcnt lgkmcnt(0)\ns_barrier" ::: "memory");
}
// extract C[dup] from f32x4 with static cndmask tree (no runtime array idx)
__device__ __forceinline__ float csel(f32x4 C, bool d1, bool d2) {
    float ca = d1 ? C[1] : C[0];
    float cb = d1 ? C[3] : C[2];
    return d2 ? cb : ca;
}
// scaled variant: w -> f16(w * s). Folds log2(e) into gate weights so the
// scan's sigmoid/tanh use raw v_exp_f32 (exp2) with no pre-multiply.
__device__ __forceinline__ half8 load_wrow8s(const float* p, float s) {
    const float4* q = (const float4*)p;
    float4 a = q[0], b = q[1];
    half8 r;
    r[0] = (_Float16)(a.x * s); r[1] = (_Float16)(a.y * s);
    r[2] = (_Float16)(a.z * s); r[3] = (_Float16)(a.w * s);
    r[4] = (_Float16)(b.x * s); r[5] = (_Float16)(b.y * s);
    r[6] = (_Float16)(b.z * s); r[7] = (_Float16)(b.w * s);
    return r;
}
// split f32x8 into hi(f16) + lo(f16 of residual): hi+lo reproduces f32 to ~2^-22
__device__ __forceinline__ void split8(const float* v, half8& hi, half8& lo) {
    #pragma unroll
    for (int j = 0; j < 8; ++j) {
        _Float16 h = (_Float16)v[j];
        hi[j] = h;
        lo[j] = (_Float16)(v[j] - (float)h);
    }
}
#define MM16(A_, B_, C_) __builtin_amdgcn_mfma_f32_16x16x32_f16(A_, B_, C_, 0, 0, 0)

// ---------------------------------------------------------------------------
// K1: dilated conv + BN + exact GELU via MFMA (split-f16 for f32 accuracy).
// 64-t tiles (19 KB LDS -> 8 blocks/CU). x staged into LDS once (coalesced,
// pre-split hi/lo); z stored via LDS transpose tile (coalesced stores).
// ---------------------------------------------------------------------------
__global__ __launch_bounds__(256) void conv_mfma_kernel(
    const float* __restrict__ x, const float* __restrict__ mix_w,
    const float* __restrict__ bn_g, const float* __restrict__ bn_b,
    const float* __restrict__ bn_m, const float* __restrict__ bn_v,
    u32* __restrict__ z_out)
{
    __shared__ __align__(16) u32 xs[68 * 68];
    __shared__ __align__(8)  u32 zt[16 * 34];

    const int b   = blockIdx.y;
    const int t0  = blockIdx.x * 64;
    const int tid = threadIdx.x;
    const int wv = tid >> 6;
    const int lane = tid & 63;
    const int lane15 = lane & 15;
    const int quad = lane >> 4;

    {
        const float* xb = x + (size_t)b * TT * FF;
        for (int idx = tid; idx < 68 * 32; idx += 256) {
            const int row = idx >> 5;
            const int fp  = (idx & 31) * 2;
            const int t = t0 - 2 + row;
            float v0 = 0.f, v1 = 0.f;
            if (t >= 0 && t < TT) {
                float2 v = *(const float2*)(xb + (size_t)t * FF + fp);
                v0 = v.x; v1 = v.y;
            }
            _Float16 h0 = (_Float16)v0, h1 = (_Float16)v1;
            _Float16 l0 = (_Float16)(v0 - (float)h0);
            _Float16 l1 = (_Float16)(v1 - (float)h1);
            u32* rw = xs + row * 68;
            rw[(fp >> 1)]      = packhh(h0, h1);
            rw[32 + (fp >> 1)] = packhh(l0, l1);
        }
    }

    half8 Ahi[6], Alo[6];
    {
        const int fo = wv * 16 + lane15;
        const float* wrow = mix_w + fo * 192;
        #pragma unroll
        for (int s = 0; s < 6; ++s) {
            float wf[8];
            #pragma unroll
            for (int j = 0; j < 8; ++j) {
                int kap = s * 32 + quad * 8 + j;
                wf[j] = wrow[(kap & 63) * 3 + (kap >> 6)];
            }
            split8(wf, Ahi[s], Alo[s]);
        }
    }
    float sc[4], sh[4];
    #pragma unroll
    for (int r = 0; r < 4; ++r) {
        int f = wv * 16 + quad * 4 + r;
        float scl = bn_g[f] * rsqrtf(bn_v[f] + 1e-5f);
        sc[r] = scl; sh[r] = bn_b[f] - bn_m[f] * scl;
    }

    __syncthreads();

    u32* zrow = z_out + (size_t)(b >> 4) * TT * 512 + (b & 15) * 32;
    const int srow = tid >> 4;
    const int sc2  = tid & 15;

    for (int tt = 0; tt < 4; ++tt) {
        f32x4 C = {0.f, 0.f, 0.f, 0.f};
        #pragma unroll
        for (int s = 0; s < 6; ++s) {
            const int row = tt * 16 + lane15 + 2 * (s >> 1);
            const u32* rp = xs + row * 68 + (s & 1) * 16 + quad * 4;
            half8 Bhi = __builtin_bit_cast(half8, *(const uint4*)(rp));
            half8 Blo = __builtin_bit_cast(half8, *(const uint4*)(rp + 32));
            C = MM16(Ahi[s], Bhi, C);
            C = MM16(Ahi[s], Blo, C);
            C = MM16(Alo[s], Bhi, C);
        }
        float z0 = gelu_exact(fmaf(C[0], sc[0], sh[0]));
        float z1 = gelu_exact(fmaf(C[1], sc[1], sh[1]));
        float z2 = gelu_exact(fmaf(C[2], sc[2], sh[2]));
        float z3 = gelu_exact(fmaf(C[3], sc[3], sh[3]));
        const u32 q0 = packh2(z0, z1);
        const u32 q1 = packh2(z2, z3);
        __syncthreads();
        *(uint2*)(zt + lane15 * 34 + wv * 8 + quad * 2) = (uint2){q0, q1};
        __syncthreads();
        uint2 v = *(const uint2*)(zt + srow * 34 + sc2 * 2);
        *(uint2*)(zrow + (size_t)(t0 + tt * 16 + srow) * 512 + sc2 * 2) = v;
    }
}

// ---------------------------------------------------------------------------
// GEMM device body (MFMA): xg[t][tile][chain][n'/2] f16 pairs. 512 workers.
// TG=4 t per block per half-stage; tbase = (gidx&15)*4 + h*64.
// Weights/biases pre-scaled by L2E (r,z: tiles 0..19) / TL2E (n: 20..29).
// ---------------------------------------------------------------------------
#define DECLAI(i) half8 A##i##_0, A##i##_1, A##i##_2, A##i##_3, A##i##_4;
#define GLOADA(i) { int tl = wv4 + (i); int rowc = tl < 30 ? tl * 16 + lane15 : 479; \
    float sA = tl < 20 ? L2E : TL2E;                                                 \
    const float* wp = W + (size_t)rowc * K + quad * 8;                               \
    A##i##_0 = load_wrow8s(wp, sA); A##i##_1 = load_wrow8s(wp + 32, sA);             \
    if (KT > 2) { A##i##_2 = load_wrow8s(wp + 64, sA);                               \
                  A##i##_3 = load_wrow8s(wp + 96, sA);                               \
                  A##i##_4 = load_wrow8s(wp + 128, sA); }                            \
    else { A##i##_2 = A##i##_0; A##i##_3 = A##i##_0; A##i##_4 = A##i##_0; } }
#define GMM(i, kt) C##i = MM16(A##i##_##kt, Bk##kt, C##i);

template<int K, int KT, int TG>
__device__ __forceinline__ void gemm_body(
    const unsigned short* __restrict__ in,
    size_t in_blk_stride, int t_off,
    const float* __restrict__ W, const float* __restrict__ b_ih,
    const float* __restrict__ b_hh, u32* __restrict__ xg,
    int gidx, int h, int tid)
{
    if (tid >= 512) return;
    const int wv4 = (tid >> 6) * 4;
    const int lane = tid & 63;
    const int lane15 = lane & 15;
    const int quad = lane >> 4;
    const int blk = gidx >> 4;
    const int tbase = (gidx & 15) * TG + h * 64;

    DECLAI(0) DECLAI(1) DECLAI(2) DECLAI(3)
    GLOADA(0) GLOADA(1) GLOADA(2) GLOADA(3)

    f32x4 BIAS0, BIAS1, BIAS2, BIAS3;
    #define GBIAS(i) { int tl = wv4 + (i); int rowb = tl < 30 ? tl * 16 + quad * 4 : 476; \
        float sB = tl < 20 ? L2E : TL2E;                                                  \
        float4 bi = *(const float4*)(b_ih + rowb);                                        \
        if (tl < 20) { float4 bh = *(const float4*)(b_hh + rowb);                         \
            bi.x += bh.x; bi.y += bh.y; bi.z += bh.z; bi.w += bh.w; }                     \
        BIAS##i[0] = bi.x * sB; BIAS##i[1] = bi.y * sB;                                   \
        BIAS##i[2] = bi.z * sB; BIAS##i[3] = bi.w * sB; }
    GBIAS(0) GBIAS(1) GBIAS(2) GBIAS(3)
    #undef GBIAS

    const unsigned short* inb = in + (size_t)blk * in_blk_stride;
    u32* xgb = xg + (size_t)blk * TC * 3840;

    for (int t = 0; t < TG; ++t) {
        const int tt = tbase + t;
        const unsigned short* ip =
            inb + ((size_t)(t_off + tt) * 16 + lane15) * K + quad * 8;
        half8 Bk0 = __builtin_bit_cast(half8, *(const uint4*)(ip));
        half8 Bk1 = __builtin_bit_cast(half8, *(const uint4*)(ip + 32));
        half8 Bk2 = Bk0, Bk3 = Bk0, Bk4 = Bk0;
        if (KT > 2) {
            Bk2 = __builtin_bit_cast(half8, *(const uint4*)(ip + 64));
            Bk3 = __builtin_bit_cast(half8, *(const uint4*)(ip + 96));
            Bk4 = __builtin_bit_cast(half8, *(const uint4*)(ip + 128));
        }
        f32x4 C0 = BIAS0, C1 = BIAS1, C2 = BIAS2, C3 = BIAS3;
        GMM(0, 0) GMM(1, 0) GMM(2, 0) GMM(3, 0)
        GMM(0, 1) GMM(1, 1) GMM(2, 1) GMM(3, 1)
        if (KT > 2) {
            GMM(0, 2) GMM(1, 2) GMM(2, 2) GMM(3, 2)
            GMM(0, 3) GMM(1, 3) GMM(2, 3) GMM(3, 3)
            GMM(0, 4) GMM(1, 4) GMM(2, 4) GMM(3, 4)
        }
        #define GSTORE(i) { int tl = wv4 + (i); if (tl < 30) {                      \
            u32 q0 = packh2(C##i[0], C##i[1]);                                      \
            u32 q1 = packh2(C##i[2], C##i[3]);                                      \
            *(uint2*)(xgb + (((size_t)tt * 30 + tl) * 16 + lane15) * 8 + quad * 2)  \
                = (uint2){q0, q1}; } }
        GSTORE(0) GSTORE(1) GSTORE(2) GSTORE(3)
        #undef GSTORE
    }
}

// ---------------------------------------------------------------------------
// Scan device body: 640 threads, 10 waves, 4 chains per block, 64 steps
// (half-chunk). Chains duplicated 4x across B-columns; dup = lane15>>2 picks
// 1 of the 4 C-rows: each lane computes ONE gate triple (6 trans + ~25 VALU).
// LDS per parity: [chain:4][208 u16] (416 B stride -> bank phases {0,8,16,24},
// every bank exactly 2-way on ds_read_b128 = conflict-free; verified R10).
// MFMA order: Cr chain first, Cn second, Cz last -> the serial r->e->n trans
// chain starts ~8 MFMA-slots earlier; Cz's MFMAs overlap it (u needed last).
// ---------------------------------------------------------------------------
#define DECLW(nm) half8 nm##0, nm##1, nm##2, nm##3, nm##4;
#define LOADWHS(nm, tb, S) { const float* wp = w_hh + (size_t)((tb) * 16 + lane15) * HH + quad * 8; \
    nm##0 = load_wrow8s(wp, S);       nm##1 = load_wrow8s(wp + 32, S);                              \
    nm##2 = load_wrow8s(wp + 64, S);  nm##3 = load_wrow8s(wp + 96, S);                              \
    nm##4 = load_wrow8s(wp + 128, S); }

template<bool WRITE_H>
__device__ __forceinline__ void scan_body(
    const u32* __restrict__ xg,          // f16 pairs [4][TC][30][16][8] u32 (parity applied)
    const float* __restrict__ w_hh, const float* __restrict__ b_hh,
    float* __restrict__ h_state,         // [64][160] f32 carry
    u32* __restrict__ h_out32,           // [4][TC][16][160] f16 (if WRITE_H, parity applied)
    int first, int blk, int sub, int h, int tid, u32* h_lds32)
{
    const int wv = tid >> 6;
    const int lane = tid & 63;
    const int lane15 = lane & 15;
    const int quad = lane >> 4;
    const int ch   = lane15 & 3;      // chain within the block's 4
    const int dup  = lane15 >> 2;     // row select within C (0..3)
    const int ch0  = sub * 4;         // global chain base within blk
    const int row_g = wv * 16 + quad * 4 + dup;   // h row this lane owns
    const u32 shamt = (u32)(16 * (dup & 1));
    const bool d1 = (dup & 1) != 0;
    const bool d2 = (dup & 2) != 0;

    DECLW(Ar) DECLW(Az) DECLW(An)
    LOADWHS(Ar, wv, L2E) LOADWHS(Az, 10 + wv, L2E) LOADWHS(An, 20 + wv, TL2E)

    const float bh = b_hh[320 + row_g] * TL2E;   // n-gate hidden bias, this row

    float* hsp = h_state + (size_t)(blk * 16 + ch0 + ch) * HH + row_g;
    float ho = first ? 0.f : *hsp;

    // LDS u16 index: chain base 208 u16 (416 B) + row
    const int widx = ch * 208 + row_g;
    unsigned short* hw16 = (unsigned short*)h_lds32;
    unsigned short* HW0 = hw16 + widx;           // parity 0
    unsigned short* HW1 = hw16 + 832 + widx;     // parity 1 (416 u32)
    *HW0 = f2h(ho);

    // fragment read base (uint4 units): chain*26 + quad; slice stride 4
    const int vb = ch * 26 + quad;

    const u32* xgb = xg + (size_t)blk * TC * 3840 + (size_t)h * 64 * 3840;
    const int pr = quad * 2 + (dup >> 1);        // u32 pair slot within tile row
    const int xo_r = ((wv)      * 16 + ch0 + ch) * 8 + pr;
    const int xo_z = ((10 + wv) * 16 + ch0 + ch) * 8 + pr;
    const int xo_n = ((20 + wv) * 16 + ch0 + ch) * 8 + pr;

    // 4-deep prefetch ring: 3 u32 per step
    u32 xrP0 = xgb[0 * 3840 + xo_r], xzP0 = xgb[0 * 3840 + xo_z], xnP0 = xgb[0 * 3840 + xo_n];
    u32 xrP1 = xgb[1 * 3840 + xo_r], xzP1 = xgb[1 * 3840 + xo_z], xnP1 = xgb[1 * 3840 + xo_n];
    u32 xrP2 = xgb[2 * 3840 + xo_r], xzP2 = xgb[2 * 3840 + xo_z], xnP2 = xgb[2 * 3840 + xo_n];
    u32 xrP3 = xgb[3 * 3840 + xo_r], xzP3 = xgb[3 * 3840 + xo_z], xnP3 = xgb[3 * 3840 + xo_n];
    const u32* pf_r = xgb + 4 * 3840 + xo_r;
    const u32* pf_z = xgb + 4 * 3840 + xo_z;
    const u32* pf_n = xgb + 4 * 3840 + xo_n;

    // h1c: f16 at [blk][t][chain 16][row 160]
    unsigned short* hp = WRITE_H
            ? (unsigned short*)h_out32 + (size_t)blk * TC * 2560
              + (size_t)h * 64 * 2560 + (size_t)(ch0 + ch) * 160 + row_g
            : nullptr;
    __syncthreads();

    #define SCAN_STEP(RBOFF, HWP, XR, XZ, XN, PFO, HPO)                              \
    {                                                                                \
        const uint4* hb = (const uint4*)(h_lds32 + (RBOFF));                         \
        uint4 b0 = hb[vb];      uint4 b1 = hb[vb + 4];                               \
        uint4 b2 = hb[vb + 8];  uint4 b3 = hb[vb + 12];                              \
        uint4 b4 = hb[vb + 16];                                                      \
        float xrv = h2sel(XR, shamt);                                                \
        float xzv = h2sel(XZ, shamt);                                                \
        float xnv = h2sel(XN, shamt);                                                \
        f32x4 Cr = {xrv, xrv, xrv, xrv};                                             \
        f32x4 Cz = {xzv, xzv, xzv, xzv};                                             \
        f32x4 Cn = {bh, bh, bh, bh};                                                 \
        XR = pf_r[PFO]; XZ = pf_z[PFO]; XN = pf_n[PFO];                              \
        half8 B0 = __builtin_bit_cast(half8, b0);                                    \
        half8 B1 = __builtin_bit_cast(half8, b1);                                    \
        half8 B2 = __builtin_bit_cast(half8, b2);                                    \
        half8 B3 = __builtin_bit_cast(half8, b3);                                    \
        half8 B4 = __builtin_bit_cast(half8, b4);                                    \
        Cr = MM16(Ar0, B0, Cr); Cr = MM16(Ar1, B1, Cr); Cr = MM16(Ar2, B2, Cr);      \
        Cr = MM16(Ar3, B3, Cr); Cr = MM16(Ar4, B4, Cr);                              \
        Cn = MM16(An0, B0, Cn); Cn = MM16(An1, B1, Cn); Cn = MM16(An2, B2, Cn);      \
        Cn = MM16(An3, B3, Cn); Cn = MM16(An4, B4, Cn);                              \
        Cz = MM16(Az0, B0, Cz); Cz = MM16(Az1, B1, Cz); Cz = MM16(Az2, B2, Cz);      \
        Cz = MM16(Az3, B3, Cz); Cz = MM16(Az4, B4, Cz);                              \
        float crv = csel(Cr, d1, d2);                                                \
        float r = frcp(1.f + fexp2(-crv));                                           \
        float cnv = csel(Cn, d1, d2);                                                \
        float e = fexp2(fmaf(r, cnv, xnv));                                          \
        float n = fmaf(-2.f, frcp(e + 1.f), 1.f);                                    \
        float czv = csel(Cz, d1, d2);                                                \
        float u = frcp(1.f + fexp2(-czv));                                           \
        ho = fmaf(u, ho - n, n);                                                     \
        const unsigned short hv = f2h(ho);                                           \
        *(HWP) = hv;                                                                 \
        if (WRITE_H) { hp[HPO] = hv; }                                               \
        barrier_lgkm();                                                              \
    }

    for (int t4 = 0; t4 < 64; t4 += 4) {
        SCAN_STEP(0,   HW1, xrP0, xzP0, xnP0, 0 * 3840, 0 * 2560)
        SCAN_STEP(416, HW0, xrP1, xzP1, xnP1, 1 * 3840, 1 * 2560)
        SCAN_STEP(0,   HW1, xrP2, xzP2, xnP2, 2 * 3840, 2 * 2560)
        SCAN_STEP(416, HW0, xrP3, xzP3, xnP3, 3 * 3840, 3 * 2560)
        pf_r += 4 * 3840; pf_z += 4 * 3840; pf_n += 4 * 3840;
        if (WRITE_H) hp += 4 * 2560;
    }
    #undef SCAN_STEP

    *hsp = ho;
}

// ---------------------------------------------------------------------------
// K2: half-chunk pipelined mega-dispatch. Stage hs (0..34) runs concurrently:
//   blocks 0..15   : scan1 chunk/half (hs-1)  [blk = bx>>2, sub = bx&3]
//   blocks 16..31  : scan2 chunk/half (hs-3)
//   blocks 32..95  : gemm1 chunk/half (hs)    [TG=4 t per block]
//   blocks 96..159 : gemm2 chunk/half (hs-2)
// where u = hs - role_offset, c = u>>1, h = u&1. Dependency edges verified:
//   gemm1(c,h)@2c+h -> scan1(c,h)@2c+1+h -> gemm2(c,h)@2c+2+h -> scan2@2c+3+h
// each crosses >=1 dispatch boundary; parity (c&1) double-buffers all
// xg1/xg2/h1c reuse with >=1 stage slack. Scan prefetch over-reads <=4 steps
// (into concurrently-written or next regions): values dead, addrs in ws.
// ---------------------------------------------------------------------------
__global__ __launch_bounds__(640, 1) void pipe_stage(
    const u32* __restrict__ z,           // [4][TT][16][32] u32
    u32* __restrict__ xg1,               // 2 x [4][TC][3840] u32
    u32* __restrict__ xg2,
    u32* __restrict__ h1c,               // 2 x [4][TC][1280] u32
    float* __restrict__ h1s, float* __restrict__ h2s,
    const float* __restrict__ w_ih1, const float* __restrict__ b_ih1,
    const float* __restrict__ w_hh1, const float* __restrict__ b_hh1,
    const float* __restrict__ w_ih2, const float* __restrict__ b_ih2,
    const float* __restrict__ w_hh2, const float* __restrict__ b_hh2,
    int hs)
{
    __shared__ __align__(16) u32 h_lds32[2 * 416];
    const int bx = blockIdx.x;
    const int tid = threadIdx.x;
    const size_t XGCH = (size_t)4 * TC * 3840;   // u32 per parity buffer
    const size_t H1CH = (size_t)4 * TC * 1280;

    if (bx < 16) {
        const int u = hs - 1;
        if (u < 0 || u >= 32) return;
        const int c = u >> 1, h = u & 1;
        scan_body<true>(xg1 + (c & 1) * XGCH, w_hh1, b_hh1, h1s,
                        h1c + (c & 1) * H1CH, u == 0, bx >> 2, bx & 3, h, tid, h_lds32);
    } else if (bx < 32) {
        const int u = hs - 3;
        if (u < 0 || u >= 32) return;
        const int c = u >> 1, h = u & 1;
        scan_body<false>(xg2 + (c & 1) * XGCH, w_hh2, b_hh2, h2s,
                         nullptr, u == 0, (bx - 16) >> 2, (bx - 16) & 3, h, tid, h_lds32);
    } else if (bx < 96) {
        const int u = hs;
        if (u >= 32) return;
        const int c = u >> 1, h = u & 1;
        gemm_body<64, 2, 4>((const unsigned short*)z, (size_t)TT * 1024, c * TC,
                            w_ih1, b_ih1, b_hh1, xg1 + (c & 1) * XGCH, bx - 32, h, tid);
    } else {
        const int u = hs - 2;
        if (u < 0 || u >= 32) return;
        const int c = u >> 1, h = u & 1;
        gemm_body<160, 5, 4>((const unsigned short*)(h1c + (c & 1) * H1CH),
                             (size_t)TC * 2560, 0,
                             w_ih2, b_ih2, b_hh2, xg2 + (c & 1) * XGCH, bx - 96, h, tid);
    }
}

// ---------------------------------------------------------------------------
// K3: MLP head from h2 final state.
// ---------------------------------------------------------------------------
__global__ __launch_bounds__(256) void head_kernel(
    const float* __restrict__ h_state,
    const float* __restrict__ hw1, const float* __restrict__ hb1,
    const float* __restrict__ hw2, const float* __restrict__ hb2,
    float* __restrict__ out)
{
    const int b = blockIdx.x;
    const int tid = threadIdx.x;
    __shared__ float hf[HH];
    __shared__ float q[80];
    if (tid < HH) hf[tid] = h_state[b * HH + tid];
    __syncthreads();
    if (tid < 80) {
        float a = hb1[tid];
        const float* wr = hw1 + (size_t)tid * HH;
        #pragma unroll 8
        for (int i = 0; i < HH; ++i) a = fmaf(wr[i], hf[i], a);
        q[tid] = gelu_exact(a);
    }
    __syncthreads();
    if (tid < 2) {
        float o = hb2[tid];
        const float* wr = hw2 + tid * 80;
        #pragma unroll 8
        for (int j = 0; j < 80; ++j) o = fmaf(wr[j], q[j], o);
        out[b * 2 + tid] = o;
    }
}

// ---------------------------------------------------------------------------
extern "C" void kernel_launch(void* const* d_in, const int* in_sizes, int n_in,
                              void* d_out, int out_size, void* d_ws, size_t ws_size,
                              hipStream_t stream)
{
    const float* x     = (const float*)d_in[0];
    const float* mix_w = (const float*)d_in[1];
    const float* bn_g  = (const float*)d_in[2];
    const float* bn_b  = (const float*)d_in[3];
    const float* bn_m  = (const float*)d_in[4];
    const float* bn_v  = (const float*)d_in[5];
    const float* w_ih1 = (const float*)d_in[6];
    const float* w_hh1 = (const float*)d_in[7];
    const float* b_ih1 = (const float*)d_in[8];
    const float* b_hh1 = (const float*)d_in[9];
    const float* w_ih2 = (const float*)d_in[10];
    const float* w_hh2 = (const float*)d_in[11];
    const float* b_ih2 = (const float*)d_in[12];
    const float* b_hh2 = (const float*)d_in[13];
    const float* hw1   = (const float*)d_in[14];
    const float* hb1   = (const float*)d_in[15];
    const float* hw2   = (const float*)d_in[16];
    const float* hb2   = (const float*)d_in[17];
    float* out = (float*)d_out;

    // ws (53.6 MB, proven-safe):
    //   z    f16 [4][T][16][64]            16.78 MB
    //   xg1  f16 2x[4][TC][30][16][16]     15.73 MB
    //   xg2  f16 2x[4][TC][30][16][16]     15.73 MB
    //   h1c  f16 2x[4][TC][16][160]         5.24 MB
    //   h1s,h2s f32 [64][160]               2 x 40 KB
    char* p = (char*)d_ws;
    u32* z_ws  = (u32*)p;  p += (size_t)BB * TT * 32 * 4;
    u32* xg1_ws = (u32*)p; p += (size_t)2 * 4 * TC * 3840 * 4;
    u32* xg2_ws = (u32*)p; p += (size_t)2 * 4 * TC * 3840 * 4;
    u32* h1c_ws = (u32*)p; p += (size_t)2 * 4 * TC * 1280 * 4;
    float* h1s = (float*)p; p += (size_t)BB * HH * 4;
    float* h2s = (float*)p;

    conv_mfma_kernel<<<dim3(32, BB), 256, 0, stream>>>(
        x, mix_w, bn_g, bn_b, bn_m, bn_v, z_ws);

    for (int hs = 0; hs < NHS; ++hs) {
        pipe_stage<<<160, 640, 0, stream>>>(
            z_ws, xg1_ws, xg2_ws, h1c_ws, h1s, h2s,
            w_ih1, b_ih1, w_hh1, b_hh1,
            w_ih2, b_ih2, w_hh2, b_hh2, hs);
    }

    head_kernel<<<BB, 256, 0, stream>>>(h2s, hw1, hb1, hw2, hb2, out);
}